// Round 2
// baseline (524.215 us; speedup 1.0000x reference)
//
#include <hip/hip_runtime.h>
#include <hip/hip_bf16.h>
#include <cstdio>

// Problem constants (B=2, T=2048, D=1024, H=4096, O=1024, E=8, top-k=2)
#define NT_TOK 4096
#define D_DIM  1024
#define H_DIM  4096
#define O_DIM  1024
#define E_NUM  8
#define PAIRS  8192      // NT_TOK * 2
#define WI_SLOTS 72      // max total m-tiles: 64 + 7 rounding < 72

typedef short bf16x8 __attribute__((ext_vector_type(8)));
typedef float f32x4  __attribute__((ext_vector_type(4)));

// round-to-nearest-even fp32 -> bf16 bits
__device__ __forceinline__ unsigned short bfr(float f){
  unsigned u = __float_as_uint(f);
  unsigned r = (u + 0x7FFFu + ((u >> 16) & 1u)) >> 16;
  return (unsigned short)r;
}

// async global->LDS, 16B per lane; lds dest is wave-uniform base (HW adds lane*16)
__device__ __forceinline__ void gload_lds16(const void* g, void* l){
  __builtin_amdgcn_global_load_lds((const __attribute__((address_space(1))) unsigned int*)g,
                                   (__attribute__((address_space(3))) unsigned int*)l,
                                   16, 0, 0);
}

// ---------------------------------------------------------------- cast x -> bf16
__global__ __launch_bounds__(256) void cast_x_kernel(const float* __restrict__ x,
                                                     unsigned short* __restrict__ xb){
  int i = blockIdx.x * 256 + threadIdx.x;           // over float4s: NT*D/4 = 1M
  const float4 v = ((const float4*)x)[i];
  unsigned short r0 = bfr(v.x), r1 = bfr(v.y), r2 = bfr(v.z), r3 = bfr(v.w);
  unsigned int p0 = (unsigned int)r0 | ((unsigned int)r1 << 16);
  unsigned int p1 = (unsigned int)r2 | ((unsigned int)r3 << 16);
  ((uint2*)xb)[i] = make_uint2(p0, p1);
}

// ------------------------- cast+transpose [R][C] f32 -> [C][R] bf16, 64x64 tiles
__global__ __launch_bounds__(256) void transpose_cast64(const float* __restrict__ in,
                                                        unsigned short* __restrict__ out,
                                                        int R, int C){
  __shared__ float t[64][65];
  long long base = (long long)blockIdx.z * R * C;
  int c0 = blockIdx.x * 64, r0 = blockIdx.y * 64;
  int tid = threadIdx.x;
  int rr = tid >> 4;           // 0..15
  int cc = (tid & 15) * 4;     // 0,4,...,60
  #pragma unroll
  for (int i = 0; i < 4; i++){
    int r = rr + i * 16;
    float4 v = *(const float4*)&in[base + (long long)(r0 + r) * C + c0 + cc];
    t[r][cc] = v.x; t[r][cc+1] = v.y; t[r][cc+2] = v.z; t[r][cc+3] = v.w;
  }
  __syncthreads();
  #pragma unroll
  for (int i = 0; i < 4; i++){
    int oc = rr + i * 16;      // output row (= input col)
    unsigned int lo = (unsigned int)bfr(t[cc][oc])   | ((unsigned int)bfr(t[cc+1][oc]) << 16);
    unsigned int hi = (unsigned int)bfr(t[cc+2][oc]) | ((unsigned int)bfr(t[cc+3][oc]) << 16);
    *(uint2*)&out[base + (long long)(c0 + oc) * R + r0 + cc] = make_uint2(lo, hi);
  }
}

// ---------------------------------------------------------------- gating (top-2)
__global__ __launch_bounds__(256) void gating_kernel(const float* __restrict__ x,
                                                     const float* __restrict__ Wg,
                                                     const float* __restrict__ bg,
                                                     int*   __restrict__ pe,
                                                     float* __restrict__ pw){
  int wid = threadIdx.x >> 6, lane = threadIdx.x & 63;
  int t = blockIdx.x * 4 + wid;
  const float* xr = x + (long long)t * D_DIM;
  float acc[E_NUM];
  #pragma unroll
  for (int e = 0; e < E_NUM; e++) acc[e] = 0.f;
  for (int d = lane; d < D_DIM; d += 64){
    float xv = xr[d];
    const float* wr = Wg + d * E_NUM;
    #pragma unroll
    for (int e = 0; e < E_NUM; e++) acc[e] += xv * wr[e];
  }
  #pragma unroll
  for (int off = 32; off; off >>= 1)
    #pragma unroll
    for (int e = 0; e < E_NUM; e++) acc[e] += __shfl_xor(acc[e], off);
  if (lane == 0){
    float l[E_NUM];
    float m = -1e30f;
    #pragma unroll
    for (int e = 0; e < E_NUM; e++){ l[e] = acc[e] + bg[e]; m = fmaxf(m, l[e]); }
    float ex[E_NUM];
    #pragma unroll
    for (int e = 0; e < E_NUM; e++) ex[e] = expf(l[e] - m);
    int e0 = 0;
    #pragma unroll
    for (int e = 1; e < E_NUM; e++) if (ex[e] > ex[e0]) e0 = e;      // first max
    int e1 = -1;
    for (int e = 0; e < E_NUM; e++){ if (e == e0) continue; if (e1 < 0 || ex[e] > ex[e1]) e1 = e; }
    float s = ex[e0] + ex[e1];
    pe[2*t]   = e0;  pw[2*t]   = ex[e0] / s;
    pe[2*t+1] = e1;  pw[2*t+1] = ex[e1] / s;
  }
}

// ---------------------------------------------------------------- chunk histograms
__global__ __launch_bounds__(256) void hist_kernel(const int* __restrict__ pe,
                                                   int* __restrict__ chunk_hist){
  __shared__ int h[E_NUM];
  if (threadIdx.x < E_NUM) h[threadIdx.x] = 0;
  __syncthreads();
  int p = blockIdx.x * 256 + threadIdx.x;
  atomicAdd(&h[pe[p]], 1);
  __syncthreads();
  if (threadIdx.x < E_NUM) chunk_hist[blockIdx.x * E_NUM + threadIdx.x] = h[threadIdx.x];
}

// --------------------------------- scan + deterministic scatter + work-item table
__global__ __launch_bounds__(256) void scatter_kernel(const int* __restrict__ pe,
                                                      const int* __restrict__ chunk_hist,
                                                      int* __restrict__ cnt,
                                                      int* __restrict__ offs,
                                                      int* __restrict__ row_pair,
                                                      int* __restrict__ wi){
  __shared__ int hist[32][E_NUM];
  __shared__ int pref[32][E_NUM];
  __shared__ int total[E_NUM];
  __shared__ int off_s[E_NUM + 1];
  __shared__ unsigned char ex[PAIRS];
  int tid = threadIdx.x;
  for (int i = tid; i < PAIRS; i += 256) ex[i] = (unsigned char)pe[i];
  { int c = tid >> 3, e = tid & 7; hist[c][e] = chunk_hist[tid]; }
  __syncthreads();
  if (tid < E_NUM){
    int s = 0;
    for (int c = 0; c < 32; c++){ pref[c][tid] = s; s += hist[c][tid]; }
    total[tid] = s;
  }
  __syncthreads();
  if (tid == 0){
    int s = 0;
    for (int e = 0; e < E_NUM; e++){ off_s[e] = s; s += total[e]; }
    off_s[E_NUM] = s;
    // work-item table: (e<<8)|mt for every valid m-tile, -1 padding
    int idx = 0;
    for (int e = 0; e < E_NUM; e++){
      int mts = (total[e] + 127) >> 7;
      for (int m = 0; m < mts; m++) wi[idx++] = (e << 8) | m;
    }
    for (; idx < WI_SLOTS; idx++) wi[idx] = -1;
  }
  __syncthreads();
  if (tid < E_NUM){ cnt[tid] = total[tid]; offs[tid] = off_s[tid]; }
  int c = tid >> 3, e = tid & 7;
  int base = off_s[e] + pref[c][e];
  int local = 0;
  for (int i = 0; i < 256; i++){
    int p = c * 256 + i;
    if (ex[p] == (unsigned char)e){
      row_pair[base + local] = p;
      local++;
    }
  }
}

// ---------------------------------------------------------------- grouped GEMM1
// hidden[pos][h] = relu( x[token(pos)] . W1[e][:, h] + b1[e][h] ), bf16 out
// 128x128 tile, BK=64, double-buffered LDS, 2-phase prefetch pipeline.
__global__ __launch_bounds__(256) void gemm1_kernel(const unsigned short* __restrict__ xb,
                                                    const unsigned short* __restrict__ W1t,
                                                    const float* __restrict__ b1,
                                                    const int* __restrict__ row_pair,
                                                    const int* __restrict__ cnt,
                                                    const int* __restrict__ offs,
                                                    const int* __restrict__ wi,
                                                    unsigned short* __restrict__ hidden){
  int w = wi[blockIdx.y];
  if (w < 0) return;
  int e = w >> 8, mt = w & 255;
  int nt = blockIdx.x;                       // 0..31  (H/128)
  int count = cnt[e];
  int m0 = mt * 128;
  int seg = offs[e];
  int valid = count - m0;
  int n0 = nt * 128;

  __shared__ unsigned short As[2][128 * 64];
  __shared__ unsigned short Bs[2][128 * 64];
  int tid = threadIdx.x;
  int wid = tid >> 6, lane = tid & 63;
  int wr = wid >> 1, wc = wid & 1;

  const unsigned short* w1e = W1t + (long long)e * H_DIM * D_DIM;   // [H][D]

  const unsigned short* aptr[4];
  const unsigned short* bptr[4];
  #pragma unroll
  for (int i = 0; i < 4; i++){
    int c = wid * 4 + i;
    int r = c * 8 + (lane >> 3);
    int pos = seg + m0 + r; if (pos > PAIRS - 1) pos = PAIRS - 1;
    int token = row_pair[pos] >> 1;
    aptr[i] = xb  + (long long)token * D_DIM + ((lane & 7) * 8);
    bptr[i] = w1e + (long long)(n0 + r) * D_DIM + ((lane & 7) * 8);
  }

  auto STAGE = [&](int b){
    #pragma unroll
    for (int i = 0; i < 4; i++){
      int c = wid * 4 + i;
      gload_lds16(aptr[i], &As[b][c * 512]);  aptr[i] += 64;
      gload_lds16(bptr[i], &Bs[b][c * 512]);  bptr[i] += 64;
    }
  };

  f32x4 acc[4][4] = {};
  auto COMPUTE = [&](int b){
    #pragma unroll
    for (int ks = 0; ks < 2; ++ks){
      bf16x8 af[4], bfv[4];
      #pragma unroll
      for (int m = 0; m < 4; m++)
        af[m] = *(const bf16x8*)&As[b][(wr*64 + m*16 + (lane & 15)) * 64 + ks*32 + ((lane >> 4) * 8)];
      #pragma unroll
      for (int n = 0; n < 4; n++)
        bfv[n] = *(const bf16x8*)&Bs[b][(wc*64 + n*16 + (lane & 15)) * 64 + ks*32 + ((lane >> 4) * 8)];
      #pragma unroll
      for (int m = 0; m < 4; m++)
        #pragma unroll
        for (int n = 0; n < 4; n++)
          acc[m][n] = __builtin_amdgcn_mfma_f32_16x16x32_bf16(af[m], bfv[n], acc[m][n], 0, 0, 0);
    }
  };

  const int KT = D_DIM / 64;                 // 16
  STAGE(0);
  __syncthreads();
  int cur = 0;
  for (int kt = 0; kt < KT - 1; ++kt){
    STAGE(cur ^ 1);          // issue next tile's loads (async, in flight under MFMA)
    COMPUTE(cur);
    __syncthreads();         // drains vmcnt (stage done) + all waves done reading cur
    cur ^= 1;
  }
  COMPUTE(cur);

  const float* b1e = b1 + (long long)e * H_DIM;
  #pragma unroll
  for (int n = 0; n < 4; n++){
    int col = n0 + wc*64 + n*16 + (lane & 15);
    float bias = b1e[col];
    #pragma unroll
    for (int m = 0; m < 4; m++){
      int rl_base = wr*64 + m*16 + ((lane >> 4) << 2);
      #pragma unroll
      for (int j = 0; j < 4; j++){
        int rl = rl_base + j;
        if (rl < valid){
          float v = acc[m][n][j] + bias;
          v = v > 0.f ? v : 0.f;
          hidden[(long long)(seg + m0 + rl) * H_DIM + col] = bfr(v);
        }
      }
    }
  }
}

// ---------------------------------------------------------------- grouped GEMM2
// split-K x2: blockIdx.z selects K-half and partial output buffer.
__global__ __launch_bounds__(256) void gemm2_kernel(const unsigned short* __restrict__ hidden,
                                                    const unsigned short* __restrict__ W2t,
                                                    const int* __restrict__ row_pair,
                                                    const int* __restrict__ cnt,
                                                    const int* __restrict__ offs,
                                                    const int* __restrict__ wi,
                                                    float* __restrict__ y0,
                                                    float* __restrict__ y1){
  int w = wi[blockIdx.y];
  if (w < 0) return;
  int e = w >> 8, mt = w & 255;
  int nt = blockIdx.x;                       // 0..7  (O/128)
  int kpart = blockIdx.z;                    // 0..1
  int count = cnt[e];
  int m0 = mt * 128;
  int seg = offs[e];
  int valid = count - m0;
  int n0 = nt * 128;
  int k0 = kpart * (H_DIM / 2);
  float* y = kpart ? y1 : y0;

  __shared__ unsigned short As[2][128 * 64];
  __shared__ unsigned short Bs[2][128 * 64];
  int tid = threadIdx.x;
  int wid = tid >> 6, lane = tid & 63;
  int wr = wid >> 1, wc = wid & 1;

  const unsigned short* w2e = W2t + (long long)e * O_DIM * H_DIM;   // [O][H]

  const unsigned short* aptr[4];
  const unsigned short* bptr[4];
  #pragma unroll
  for (int i = 0; i < 4; i++){
    int c = wid * 4 + i;
    int r = c * 8 + (lane >> 3);
    long long apos = seg + m0 + r; if (apos > PAIRS - 1) apos = PAIRS - 1;
    aptr[i] = hidden + apos * H_DIM + k0 + ((lane & 7) * 8);
    bptr[i] = w2e + (long long)(n0 + r) * H_DIM + k0 + ((lane & 7) * 8);
  }

  auto STAGE = [&](int b){
    #pragma unroll
    for (int i = 0; i < 4; i++){
      int c = wid * 4 + i;
      gload_lds16(aptr[i], &As[b][c * 512]);  aptr[i] += 64;
      gload_lds16(bptr[i], &Bs[b][c * 512]);  bptr[i] += 64;
    }
  };

  f32x4 acc[4][4] = {};
  auto COMPUTE = [&](int b){
    #pragma unroll
    for (int ks = 0; ks < 2; ++ks){
      bf16x8 af[4], bfv[4];
      #pragma unroll
      for (int m = 0; m < 4; m++)
        af[m] = *(const bf16x8*)&As[b][(wr*64 + m*16 + (lane & 15)) * 64 + ks*32 + ((lane >> 4) * 8)];
      #pragma unroll
      for (int n = 0; n < 4; n++)
        bfv[n] = *(const bf16x8*)&Bs[b][(wc*64 + n*16 + (lane & 15)) * 64 + ks*32 + ((lane >> 4) * 8)];
      #pragma unroll
      for (int m = 0; m < 4; m++)
        #pragma unroll
        for (int n = 0; n < 4; n++)
          acc[m][n] = __builtin_amdgcn_mfma_f32_16x16x32_bf16(af[m], bfv[n], acc[m][n], 0, 0, 0);
    }
  };

  const int KT = (H_DIM / 2) / 64;           // 32
  STAGE(0);
  __syncthreads();
  int cur = 0;
  for (int kt = 0; kt < KT - 1; ++kt){
    STAGE(cur ^ 1);
    COMPUTE(cur);
    __syncthreads();
    cur ^= 1;
  }
  COMPUTE(cur);

  #pragma unroll
  for (int m = 0; m < 4; m++){
    int rl_base = wr*64 + m*16 + ((lane >> 4) << 2);
    #pragma unroll
    for (int j = 0; j < 4; j++){
      int rl = rl_base + j;
      if (rl < valid){
        int p = row_pair[seg + m0 + rl];
        float* yr = y + (long long)p * O_DIM;
        #pragma unroll
        for (int n = 0; n < 4; n++){
          int col = n0 + wc*64 + n*16 + (lane & 15);
          yr[col] = acc[m][n][j];
        }
      }
    }
  }
}

// ---------------------------------------------------------------- combine
__global__ __launch_bounds__(256) void combine_kernel(const float* __restrict__ y0,
                                                      const float* __restrict__ y1,
                                                      const float* __restrict__ b2,
                                                      const int* __restrict__ pe,
                                                      const float* __restrict__ pw,
                                                      float* __restrict__ out){
  int t = blockIdx.x, tid = threadIdx.x;      // 256 threads * float4 = 1024 = O_DIM
  int e0 = pe[2*t], e1 = pe[2*t+1];
  float w0 = pw[2*t], w1 = pw[2*t+1];
  const float4* a0 = (const float4*)(y0 + (long long)(2*t) * O_DIM);
  const float4* a1 = (const float4*)(y1 + (long long)(2*t) * O_DIM);
  const float4* b0 = (const float4*)(y0 + (long long)(2*t+1) * O_DIM);
  const float4* b1v = (const float4*)(y1 + (long long)(2*t+1) * O_DIM);
  const float4* c0 = (const float4*)(b2 + (long long)e0 * O_DIM);
  const float4* c1 = (const float4*)(b2 + (long long)e1 * O_DIM);
  float4 xa = a0[tid], xb = a1[tid], ya = b0[tid], yb = b1v[tid], ca = c0[tid], cb = c1[tid];
  float4 r;
  r.x = w0 * (xa.x + xb.x + ca.x) + w1 * (ya.x + yb.x + cb.x);
  r.y = w0 * (xa.y + xb.y + ca.y) + w1 * (ya.y + yb.y + cb.y);
  r.z = w0 * (xa.z + xb.z + ca.z) + w1 * (ya.z + yb.z + cb.z);
  r.w = w0 * (xa.w + xb.w + ca.w) + w1 * (ya.w + yb.w + cb.w);
  ((float4*)(out + (long long)t * O_DIM))[tid] = r;
}

// ---------------------------------------------------------------- host
extern "C" void kernel_launch(void* const* d_in, const int* in_sizes, int n_in,
                              void* d_out, int out_size, void* d_ws, size_t ws_size,
                              hipStream_t stream){
  const float* x  = (const float*)d_in[0];
  const float* Wg = (const float*)d_in[1];
  const float* bg = (const float*)d_in[2];
  const float* W1 = (const float*)d_in[3];
  const float* b1 = (const float*)d_in[4];
  const float* W2 = (const float*)d_in[5];
  const float* b2 = (const float*)d_in[6];
  float* out = (float*)d_out;

  char* ws = (char*)d_ws;
  size_t off = 0;
  auto alloc = [&](size_t bytes){ size_t r = off; off += (bytes + 255) & ~(size_t)255; return r; };

  unsigned short* W1t    = (unsigned short*)(ws + alloc((size_t)E_NUM * H_DIM * D_DIM * 2));
  unsigned short* W2t    = (unsigned short*)(ws + alloc((size_t)E_NUM * O_DIM * H_DIM * 2));
  unsigned short* xb     = (unsigned short*)(ws + alloc((size_t)NT_TOK * D_DIM * 2));
  unsigned short* hidden = (unsigned short*)(ws + alloc((size_t)PAIRS * H_DIM * 2));
  float*          y_p0   = (float*)         (ws + alloc((size_t)PAIRS * O_DIM * 4));
  int*            pe     = (int*)           (ws + alloc(PAIRS * 4));
  float*          pw     = (float*)         (ws + alloc(PAIRS * 4));
  int*            row_pair = (int*)         (ws + alloc(PAIRS * 4));
  int*            cnt    = (int*)           (ws + alloc(64));
  int*            offs   = (int*)           (ws + alloc(64));
  int*            chist  = (int*)           (ws + alloc(32 * E_NUM * 4));
  int*            wi     = (int*)           (ws + alloc(WI_SLOTS * 4));
  // y partial 1 aliases W1t (dead after gemm1; stream order guarantees safety)
  float*          y_p1   = (float*)W1t;

  if (off > ws_size)
    fprintf(stderr, "kernel_launch: workspace too small: need %zu, have %zu\n", off, ws_size);

  cast_x_kernel<<<(NT_TOK * D_DIM / 4) / 256, 256, 0, stream>>>(x, xb);
  transpose_cast64<<<dim3(H_DIM/64, D_DIM/64, E_NUM), 256, 0, stream>>>(W1, W1t, D_DIM, H_DIM);
  transpose_cast64<<<dim3(O_DIM/64, H_DIM/64, E_NUM), 256, 0, stream>>>(W2, W2t, H_DIM, O_DIM);
  gating_kernel<<<NT_TOK/4, 256, 0, stream>>>(x, Wg, bg, pe, pw);
  hist_kernel<<<PAIRS/256, 256, 0, stream>>>(pe, chist);
  scatter_kernel<<<1, 256, 0, stream>>>(pe, chist, cnt, offs, row_pair, wi);
  gemm1_kernel<<<dim3(H_DIM/128, WI_SLOTS), 256, 0, stream>>>(xb, W1t, b1, row_pair, cnt, offs, wi, hidden);
  gemm2_kernel<<<dim3(O_DIM/128, WI_SLOTS, 2), 256, 0, stream>>>(hidden, W2t, row_pair, cnt, offs, wi, y_p0, y_p1);
  combine_kernel<<<NT_TOK, 256, 0, stream>>>(y_p0, y_p1, b2, pe, pw, out);
}

// Round 3
// 471.163 us; speedup vs baseline: 1.1126x; 1.1126x over previous
//
#include <hip/hip_runtime.h>
#include <hip/hip_bf16.h>
#include <cstdio>

// Problem constants (B=2, T=2048, D=1024, H=4096, O=1024, E=8, top-k=2)
#define NT_TOK 4096
#define D_DIM  1024
#define H_DIM  4096
#define O_DIM  1024
#define E_NUM  8
#define PAIRS  8192      // NT_TOK * 2
#define WI_SLOTS 40      // max m-tiles at BM=256: 32 + 7 rounding < 40
#define BK 64

typedef short bf16x8 __attribute__((ext_vector_type(8)));
typedef float f32x4  __attribute__((ext_vector_type(4)));

// round-to-nearest-even fp32 -> bf16 bits
__device__ __forceinline__ unsigned short bfr(float f){
  unsigned u = __float_as_uint(f);
  unsigned r = (u + 0x7FFFu + ((u >> 16) & 1u)) >> 16;
  return (unsigned short)r;
}

// async global->LDS, 16B per lane; lds dest is wave-uniform base (HW adds lane*16)
__device__ __forceinline__ void gload_lds16(const void* g, void* l){
  __builtin_amdgcn_global_load_lds((const __attribute__((address_space(1))) unsigned int*)g,
                                   (__attribute__((address_space(3))) unsigned int*)l,
                                   16, 0, 0);
}

// ---------------------------------------------------------------- cast x -> bf16
__global__ __launch_bounds__(256) void cast_x_kernel(const float* __restrict__ x,
                                                     unsigned short* __restrict__ xb){
  int i = blockIdx.x * 256 + threadIdx.x;           // over float4s: NT*D/4 = 1M
  const float4 v = ((const float4*)x)[i];
  unsigned short r0 = bfr(v.x), r1 = bfr(v.y), r2 = bfr(v.z), r3 = bfr(v.w);
  unsigned int p0 = (unsigned int)r0 | ((unsigned int)r1 << 16);
  unsigned int p1 = (unsigned int)r2 | ((unsigned int)r3 << 16);
  ((uint2*)xb)[i] = make_uint2(p0, p1);
}

// ------------------------- cast+transpose [R][C] f32 -> [C][R] bf16, 64x64 tiles
__global__ __launch_bounds__(256) void transpose_cast64(const float* __restrict__ in,
                                                        unsigned short* __restrict__ out,
                                                        int R, int C){
  __shared__ float t[64][65];
  long long base = (long long)blockIdx.z * R * C;
  int c0 = blockIdx.x * 64, r0 = blockIdx.y * 64;
  int tid = threadIdx.x;
  int rr = tid >> 4;           // 0..15
  int cc = (tid & 15) * 4;     // 0,4,...,60
  #pragma unroll
  for (int i = 0; i < 4; i++){
    int r = rr + i * 16;
    float4 v = *(const float4*)&in[base + (long long)(r0 + r) * C + c0 + cc];
    t[r][cc] = v.x; t[r][cc+1] = v.y; t[r][cc+2] = v.z; t[r][cc+3] = v.w;
  }
  __syncthreads();
  #pragma unroll
  for (int i = 0; i < 4; i++){
    int oc = rr + i * 16;      // output row (= input col)
    unsigned int lo = (unsigned int)bfr(t[cc][oc])   | ((unsigned int)bfr(t[cc+1][oc]) << 16);
    unsigned int hi = (unsigned int)bfr(t[cc+2][oc]) | ((unsigned int)bfr(t[cc+3][oc]) << 16);
    *(uint2*)&out[base + (long long)(c0 + oc) * R + r0 + cc] = make_uint2(lo, hi);
  }
}

// ---------------------------------------------------------------- gating (top-2)
__global__ __launch_bounds__(256) void gating_kernel(const float* __restrict__ x,
                                                     const float* __restrict__ Wg,
                                                     const float* __restrict__ bg,
                                                     int*   __restrict__ pe,
                                                     float* __restrict__ pw){
  int wid = threadIdx.x >> 6, lane = threadIdx.x & 63;
  int t = blockIdx.x * 4 + wid;
  const float* xr = x + (long long)t * D_DIM;
  float acc[E_NUM];
  #pragma unroll
  for (int e = 0; e < E_NUM; e++) acc[e] = 0.f;
  for (int d = lane; d < D_DIM; d += 64){
    float xv = xr[d];
    const float* wr = Wg + d * E_NUM;
    #pragma unroll
    for (int e = 0; e < E_NUM; e++) acc[e] += xv * wr[e];
  }
  #pragma unroll
  for (int off = 32; off; off >>= 1)
    #pragma unroll
    for (int e = 0; e < E_NUM; e++) acc[e] += __shfl_xor(acc[e], off);
  if (lane == 0){
    float l[E_NUM];
    float m = -1e30f;
    #pragma unroll
    for (int e = 0; e < E_NUM; e++){ l[e] = acc[e] + bg[e]; m = fmaxf(m, l[e]); }
    float ex[E_NUM];
    #pragma unroll
    for (int e = 0; e < E_NUM; e++) ex[e] = expf(l[e] - m);
    int e0 = 0;
    #pragma unroll
    for (int e = 1; e < E_NUM; e++) if (ex[e] > ex[e0]) e0 = e;      // first max
    int e1 = -1;
    for (int e = 0; e < E_NUM; e++){ if (e == e0) continue; if (e1 < 0 || ex[e] > ex[e1]) e1 = e; }
    float s = ex[e0] + ex[e1];
    pe[2*t]   = e0;  pw[2*t]   = ex[e0] / s;
    pe[2*t+1] = e1;  pw[2*t+1] = ex[e1] / s;
  }
}

// ---------------------------------------------------------------- chunk histograms
__global__ __launch_bounds__(256) void hist_kernel(const int* __restrict__ pe,
                                                   int* __restrict__ chunk_hist){
  __shared__ int h[E_NUM];
  if (threadIdx.x < E_NUM) h[threadIdx.x] = 0;
  __syncthreads();
  int p = blockIdx.x * 256 + threadIdx.x;
  atomicAdd(&h[pe[p]], 1);
  __syncthreads();
  if (threadIdx.x < E_NUM) chunk_hist[blockIdx.x * E_NUM + threadIdx.x] = h[threadIdx.x];
}

// --------------------------------- scan + deterministic scatter + work-item table
__global__ __launch_bounds__(256) void scatter_kernel(const int* __restrict__ pe,
                                                      const int* __restrict__ chunk_hist,
                                                      int* __restrict__ cnt,
                                                      int* __restrict__ offs,
                                                      int* __restrict__ row_pair,
                                                      int* __restrict__ wi){
  __shared__ int hist[32][E_NUM];
  __shared__ int pref[32][E_NUM];
  __shared__ int total[E_NUM];
  __shared__ int off_s[E_NUM + 1];
  __shared__ unsigned char ex[PAIRS];
  int tid = threadIdx.x;
  for (int i = tid; i < PAIRS; i += 256) ex[i] = (unsigned char)pe[i];
  { int c = tid >> 3, e = tid & 7; hist[c][e] = chunk_hist[tid]; }
  __syncthreads();
  if (tid < E_NUM){
    int s = 0;
    for (int c = 0; c < 32; c++){ pref[c][tid] = s; s += hist[c][tid]; }
    total[tid] = s;
  }
  __syncthreads();
  if (tid == 0){
    int s = 0;
    for (int e = 0; e < E_NUM; e++){ off_s[e] = s; s += total[e]; }
    off_s[E_NUM] = s;
    // work-item table: (e<<8)|mt for every valid 256-row m-tile, -1 padding
    int idx = 0;
    for (int e = 0; e < E_NUM; e++){
      int mts = (total[e] + 255) >> 8;
      for (int m = 0; m < mts; m++) wi[idx++] = (e << 8) | m;
    }
    for (; idx < WI_SLOTS; idx++) wi[idx] = -1;
  }
  __syncthreads();
  if (tid < E_NUM){ cnt[tid] = total[tid]; offs[tid] = off_s[tid]; }
  int c = tid >> 3, e = tid & 7;
  int base = off_s[e] + pref[c][e];
  int local = 0;
  for (int i = 0; i < 256; i++){
    int p = c * 256 + i;
    if (ex[p] == (unsigned char)e){
      row_pair[base + local] = p;
      local++;
    }
  }
}

// ============================================================== grouped GEMM1
// 256x256 tile, BK=64, 512 thr (8 waves 2x4), dbuf LDS + T2 swizzle +
// counted-vmcnt half-tile pipeline (T3/T4) + setprio (T5) + XCD chunking (T1).
// hidden[pos][h] = relu( x[token(pos)] . W1[e][:, h] + b1[e][h] ), bf16 out
#define NWG1 640   // 16 n-tiles * 40 slots
#define CH1  80    // NWG1 / 8
__global__ __launch_bounds__(512, 2) void gemm1_kernel(const unsigned short* __restrict__ xb,
                                                       const unsigned short* __restrict__ W1t,
                                                       const float* __restrict__ b1,
                                                       const int* __restrict__ row_pair,
                                                       const int* __restrict__ cnt,
                                                       const int* __restrict__ offs,
                                                       const int* __restrict__ wi,
                                                       unsigned short* __restrict__ hidden){
  // XCD-chunked block permutation (bijective: 640 % 8 == 0)
  int f  = blockIdx.y * 16 + blockIdx.x;
  int fp = (f & 7) * CH1 + (f >> 3);
  int nt   = fp & 15;
  int slot = fp >> 4;
  int w = wi[slot];
  if (w < 0) return;
  int e = w >> 8, mt = w & 255;
  int count = cnt[e];
  int m0 = mt * 256;
  int seg = offs[e];
  int valid = count - m0;
  int n0 = nt * 256;

  __shared__ unsigned short As[2][256 * BK];
  __shared__ unsigned short Bs[2][256 * BK];

  int tid = threadIdx.x;
  int wv = tid >> 6, lane = tid & 63;
  int wr = wv >> 2, wc = wv & 3;          // 2 x 4 waves; wave owns rows {mh*128+wr*64..+63}, cols wc*64..+63
  int lo = lane & 15, hi = lane >> 4;
  int l3 = lane >> 3;
  int srcel = ((lane & 7) ^ l3) << 3;     // inverse-swizzled source column (elements)

  const unsigned short* w1e = W1t + (long long)e * H_DIM * D_DIM;   // [H][D]

  // stage pointers: pa/pb[half][g] covers LDS rows half*128 + wv*16 + g*8 + (lane>>3)
  const unsigned short* pa[2][2];
  const unsigned short* pb[2][2];
  #pragma unroll
  for (int h = 0; h < 2; h++)
    #pragma unroll
    for (int g = 0; g < 2; g++){
      int rloc = h * 128 + wv * 16 + g * 8 + l3;
      int pos = seg + m0 + rloc; if (pos > PAIRS - 1) pos = PAIRS - 1;
      int token = row_pair[pos] >> 1;
      pa[h][g] = xb + (long long)token * D_DIM + srcel;
      pb[h][g] = w1e + (long long)(n0 + rloc) * D_DIM + srcel;
    }

  auto STG_A = [&](int b, int h){
    gload_lds16(pa[h][0], &As[b][(h*128 + wv*16    ) * BK]);  pa[h][0] += BK;
    gload_lds16(pa[h][1], &As[b][(h*128 + wv*16 + 8) * BK]);  pa[h][1] += BK;
  };
  auto STG_B = [&](int b, int h){
    gload_lds16(pb[h][0], &Bs[b][(h*128 + wv*16    ) * BK]);  pb[h][0] += BK;
    gload_lds16(pb[h][1], &Bs[b][(h*128 + wv*16 + 8) * BK]);  pb[h][1] += BK;
  };

  f32x4 acc[2][4][4] = {};
  auto PH = [&](int b, int ks, int mh){
    bf16x8 aq[4], bq[4];
    #pragma unroll
    for (int n = 0; n < 4; n++){
      int br = wc*64 + n*16 + lo;
      bq[n] = *(const bf16x8*)&Bs[b][br*BK + ((ks*32 + hi*8) ^ ((br & 7) << 3))];
    }
    #pragma unroll
    for (int i = 0; i < 4; i++){
      int ar = mh*128 + wr*64 + i*16 + lo;
      aq[i] = *(const bf16x8*)&As[b][ar*BK + ((ks*32 + hi*8) ^ ((ar & 7) << 3))];
    }
    __builtin_amdgcn_s_setprio(1);
    #pragma unroll
    for (int i = 0; i < 4; i++)
      #pragma unroll
      for (int n = 0; n < 4; n++)
        acc[mh][i][n] = __builtin_amdgcn_mfma_f32_16x16x32_bf16(aq[i], bq[n], acc[mh][i][n], 0, 0, 0);
    __builtin_amdgcn_s_setprio(0);
  };

  const int KT = D_DIM / BK;                 // 16
  // prologue: tile 0 fully staged
  STG_B(0, 0); STG_B(0, 1); STG_A(0, 0); STG_A(0, 1);
  asm volatile("s_waitcnt vmcnt(0)" ::: "memory");
  __builtin_amdgcn_s_barrier();
  int cur = 0;
  for (int kt = 0; kt < KT - 1; ++kt){
    int nx = cur ^ 1;
    STG_B(nx, 0);
    PH(cur, 0, 0);
    STG_B(nx, 1);
    PH(cur, 1, 0);
    STG_A(nx, 0);
    // drain prev A1 (oldest 2 of 8 outstanding), collectively guaranteed by barrier
    asm volatile("s_waitcnt vmcnt(6)" ::: "memory");
    __builtin_amdgcn_s_barrier();
    PH(cur, 0, 1);
    STG_A(nx, 1);
    PH(cur, 1, 1);
    // drain next tile's B0,B1,A0 (oldest 6); A1 stays in flight across barrier
    asm volatile("s_waitcnt vmcnt(2)" ::: "memory");
    __builtin_amdgcn_s_barrier();
    cur = nx;
  }
  // final tile (no staging)
  PH(cur, 0, 0);
  PH(cur, 1, 0);
  asm volatile("s_waitcnt vmcnt(0)" ::: "memory");
  __builtin_amdgcn_s_barrier();
  PH(cur, 0, 1);
  PH(cur, 1, 1);

  const float* b1e = b1 + (long long)e * H_DIM;
  #pragma unroll
  for (int n = 0; n < 4; n++){
    int col = n0 + wc*64 + n*16 + lo;
    float bias = b1e[col];
    #pragma unroll
    for (int mh = 0; mh < 2; mh++)
      #pragma unroll
      for (int i = 0; i < 4; i++)
        #pragma unroll
        for (int j = 0; j < 4; j++){
          int rl = mh*128 + wr*64 + i*16 + hi*4 + j;
          if (rl < valid){
            float v = acc[mh][i][n][j] + bias;
            v = v > 0.f ? v : 0.f;
            hidden[(long long)(seg + m0 + rl) * H_DIM + col] = bfr(v);
          }
        }
  }
}

// ============================================================== grouped GEMM2
// same structure; split-K x2 (blockIdx.z), y = hidden . W2[e]^T (scattered out)
#define NWG2 320   // 4 n-tiles * 40 slots * 2 kparts
#define CH2  40    // NWG2 / 8
__global__ __launch_bounds__(512, 2) void gemm2_kernel(const unsigned short* __restrict__ hidden,
                                                       const unsigned short* __restrict__ W2t,
                                                       const int* __restrict__ row_pair,
                                                       const int* __restrict__ cnt,
                                                       const int* __restrict__ offs,
                                                       const int* __restrict__ wi,
                                                       float* __restrict__ y0,
                                                       float* __restrict__ y1){
  int f  = (blockIdx.z * WI_SLOTS + blockIdx.y) * 4 + blockIdx.x;
  int fp = (f & 7) * CH2 + (f >> 3);
  int nt   = fp & 3;
  int r2   = fp >> 2;
  int kpart = r2 / WI_SLOTS;
  int slot  = r2 % WI_SLOTS;
  int w = wi[slot];
  if (w < 0) return;
  int e = w >> 8, mt = w & 255;
  int count = cnt[e];
  int m0 = mt * 256;
  int seg = offs[e];
  int valid = count - m0;
  int n0 = nt * 256;
  int k0 = kpart * (H_DIM / 2);
  float* y = kpart ? y1 : y0;

  __shared__ unsigned short As[2][256 * BK];
  __shared__ unsigned short Bs[2][256 * BK];

  int tid = threadIdx.x;
  int wv = tid >> 6, lane = tid & 63;
  int wr = wv >> 2, wc = wv & 3;
  int lo = lane & 15, hi = lane >> 4;
  int l3 = lane >> 3;
  int srcel = ((lane & 7) ^ l3) << 3;

  const unsigned short* w2e = W2t + (long long)e * O_DIM * H_DIM;   // [O][H]

  const unsigned short* pa[2][2];
  const unsigned short* pb[2][2];
  #pragma unroll
  for (int h = 0; h < 2; h++)
    #pragma unroll
    for (int g = 0; g < 2; g++){
      int rloc = h * 128 + wv * 16 + g * 8 + l3;
      long long pos = seg + m0 + rloc; if (pos > PAIRS - 1) pos = PAIRS - 1;
      pa[h][g] = hidden + pos * H_DIM + k0 + srcel;
      pb[h][g] = w2e + (long long)(n0 + rloc) * H_DIM + k0 + srcel;
    }

  auto STG_A = [&](int b, int h){
    gload_lds16(pa[h][0], &As[b][(h*128 + wv*16    ) * BK]);  pa[h][0] += BK;
    gload_lds16(pa[h][1], &As[b][(h*128 + wv*16 + 8) * BK]);  pa[h][1] += BK;
  };
  auto STG_B = [&](int b, int h){
    gload_lds16(pb[h][0], &Bs[b][(h*128 + wv*16    ) * BK]);  pb[h][0] += BK;
    gload_lds16(pb[h][1], &Bs[b][(h*128 + wv*16 + 8) * BK]);  pb[h][1] += BK;
  };

  f32x4 acc[2][4][4] = {};
  auto PH = [&](int b, int ks, int mh){
    bf16x8 aq[4], bq[4];
    #pragma unroll
    for (int n = 0; n < 4; n++){
      int br = wc*64 + n*16 + lo;
      bq[n] = *(const bf16x8*)&Bs[b][br*BK + ((ks*32 + hi*8) ^ ((br & 7) << 3))];
    }
    #pragma unroll
    for (int i = 0; i < 4; i++){
      int ar = mh*128 + wr*64 + i*16 + lo;
      aq[i] = *(const bf16x8*)&As[b][ar*BK + ((ks*32 + hi*8) ^ ((ar & 7) << 3))];
    }
    __builtin_amdgcn_s_setprio(1);
    #pragma unroll
    for (int i = 0; i < 4; i++)
      #pragma unroll
      for (int n = 0; n < 4; n++)
        acc[mh][i][n] = __builtin_amdgcn_mfma_f32_16x16x32_bf16(aq[i], bq[n], acc[mh][i][n], 0, 0, 0);
    __builtin_amdgcn_s_setprio(0);
  };

  const int KT = (H_DIM / 2) / BK;           // 32
  STG_B(0, 0); STG_B(0, 1); STG_A(0, 0); STG_A(0, 1);
  asm volatile("s_waitcnt vmcnt(0)" ::: "memory");
  __builtin_amdgcn_s_barrier();
  int cur = 0;
  for (int kt = 0; kt < KT - 1; ++kt){
    int nx = cur ^ 1;
    STG_B(nx, 0);
    PH(cur, 0, 0);
    STG_B(nx, 1);
    PH(cur, 1, 0);
    STG_A(nx, 0);
    asm volatile("s_waitcnt vmcnt(6)" ::: "memory");
    __builtin_amdgcn_s_barrier();
    PH(cur, 0, 1);
    STG_A(nx, 1);
    PH(cur, 1, 1);
    asm volatile("s_waitcnt vmcnt(2)" ::: "memory");
    __builtin_amdgcn_s_barrier();
    cur = nx;
  }
  PH(cur, 0, 0);
  PH(cur, 1, 0);
  asm volatile("s_waitcnt vmcnt(0)" ::: "memory");
  __builtin_amdgcn_s_barrier();
  PH(cur, 0, 1);
  PH(cur, 1, 1);

  #pragma unroll
  for (int mh = 0; mh < 2; mh++)
    #pragma unroll
    for (int i = 0; i < 4; i++)
      #pragma unroll
      for (int j = 0; j < 4; j++){
        int rl = mh*128 + wr*64 + i*16 + hi*4 + j;
        if (rl < valid){
          int p = row_pair[seg + m0 + rl];
          float* yr = y + (long long)p * O_DIM;
          #pragma unroll
          for (int n = 0; n < 4; n++){
            int col = n0 + wc*64 + n*16 + lo;
            yr[col] = acc[mh][i][n][j];
          }
        }
      }
}

// ---------------------------------------------------------------- combine
__global__ __launch_bounds__(256) void combine_kernel(const float* __restrict__ y0,
                                                      const float* __restrict__ y1,
                                                      const float* __restrict__ b2,
                                                      const int* __restrict__ pe,
                                                      const float* __restrict__ pw,
                                                      float* __restrict__ out){
  int t = blockIdx.x, tid = threadIdx.x;      // 256 threads * float4 = 1024 = O_DIM
  int e0 = pe[2*t], e1 = pe[2*t+1];
  float w0 = pw[2*t], w1 = pw[2*t+1];
  const float4* a0 = (const float4*)(y0 + (long long)(2*t) * O_DIM);
  const float4* a1 = (const float4*)(y1 + (long long)(2*t) * O_DIM);
  const float4* b0 = (const float4*)(y0 + (long long)(2*t+1) * O_DIM);
  const float4* b1v = (const float4*)(y1 + (long long)(2*t+1) * O_DIM);
  const float4* c0 = (const float4*)(b2 + (long long)e0 * O_DIM);
  const float4* c1 = (const float4*)(b2 + (long long)e1 * O_DIM);
  float4 xa = a0[tid], xb = a1[tid], ya = b0[tid], yb = b1v[tid], ca = c0[tid], cb = c1[tid];
  float4 r;
  r.x = w0 * (xa.x + xb.x + ca.x) + w1 * (ya.x + yb.x + cb.x);
  r.y = w0 * (xa.y + xb.y + ca.y) + w1 * (ya.y + yb.y + cb.y);
  r.z = w0 * (xa.z + xb.z + ca.z) + w1 * (ya.z + yb.z + cb.z);
  r.w = w0 * (xa.w + xb.w + ca.w) + w1 * (ya.w + yb.w + cb.w);
  ((float4*)(out + (long long)t * O_DIM))[tid] = r;
}

// ---------------------------------------------------------------- host
extern "C" void kernel_launch(void* const* d_in, const int* in_sizes, int n_in,
                              void* d_out, int out_size, void* d_ws, size_t ws_size,
                              hipStream_t stream){
  const float* x  = (const float*)d_in[0];
  const float* Wg = (const float*)d_in[1];
  const float* bg = (const float*)d_in[2];
  const float* W1 = (const float*)d_in[3];
  const float* b1 = (const float*)d_in[4];
  const float* W2 = (const float*)d_in[5];
  const float* b2 = (const float*)d_in[6];
  float* out = (float*)d_out;

  char* ws = (char*)d_ws;
  size_t off = 0;
  auto alloc = [&](size_t bytes){ size_t r = off; off += (bytes + 255) & ~(size_t)255; return r; };

  unsigned short* W1t    = (unsigned short*)(ws + alloc((size_t)E_NUM * H_DIM * D_DIM * 2));
  unsigned short* W2t    = (unsigned short*)(ws + alloc((size_t)E_NUM * O_DIM * H_DIM * 2));
  unsigned short* xb     = (unsigned short*)(ws + alloc((size_t)NT_TOK * D_DIM * 2));
  unsigned short* hidden = (unsigned short*)(ws + alloc((size_t)PAIRS * H_DIM * 2));
  float*          y_p0   = (float*)         (ws + alloc((size_t)PAIRS * O_DIM * 4));
  int*            pe     = (int*)           (ws + alloc(PAIRS * 4));
  float*          pw     = (float*)         (ws + alloc(PAIRS * 4));
  int*            row_pair = (int*)         (ws + alloc(PAIRS * 4));
  int*            cnt    = (int*)           (ws + alloc(64));
  int*            offs   = (int*)           (ws + alloc(64));
  int*            chist  = (int*)           (ws + alloc(32 * E_NUM * 4));
  int*            wi     = (int*)           (ws + alloc(WI_SLOTS * 4));
  // y partial 1 aliases W1t (dead after gemm1; stream order guarantees safety)
  float*          y_p1   = (float*)W1t;

  if (off > ws_size)
    fprintf(stderr, "kernel_launch: workspace too small: need %zu, have %zu\n", off, ws_size);

  cast_x_kernel<<<(NT_TOK * D_DIM / 4) / 256, 256, 0, stream>>>(x, xb);
  transpose_cast64<<<dim3(H_DIM/64, D_DIM/64, E_NUM), 256, 0, stream>>>(W1, W1t, D_DIM, H_DIM);
  transpose_cast64<<<dim3(O_DIM/64, H_DIM/64, E_NUM), 256, 0, stream>>>(W2, W2t, H_DIM, O_DIM);
  gating_kernel<<<NT_TOK/4, 256, 0, stream>>>(x, Wg, bg, pe, pw);
  hist_kernel<<<PAIRS/256, 256, 0, stream>>>(pe, chist);
  scatter_kernel<<<1, 256, 0, stream>>>(pe, chist, cnt, offs, row_pair, wi);
  gemm1_kernel<<<dim3(H_DIM/256, WI_SLOTS), 512, 0, stream>>>(xb, W1t, b1, row_pair, cnt, offs, wi, hidden);
  gemm2_kernel<<<dim3(O_DIM/256, WI_SLOTS, 2), 512, 0, stream>>>(hidden, W2t, row_pair, cnt, offs, wi, y_p0, y_p1);
  combine_kernel<<<NT_TOK, 256, 0, stream>>>(y_p0, y_p1, b2, pe, pw, out);
}

// Round 4
// 402.337 us; speedup vs baseline: 1.3029x; 1.1711x over previous
//
#include <hip/hip_runtime.h>
#include <hip/hip_bf16.h>
#include <cstdio>

// Problem constants (B=2, T=2048, D=1024, H=4096, O=1024, E=8, top-k=2)
#define NT_TOK 4096
#define D_DIM  1024
#define H_DIM  4096
#define O_DIM  1024
#define E_NUM  8
#define PAIRS  8192      // NT_TOK * 2
#define WI_SLOTS 40      // max m-tiles at BM=256: 32 + 7 rounding < 40
#define BK 64

typedef short bf16x8 __attribute__((ext_vector_type(8)));
typedef float f32x4  __attribute__((ext_vector_type(4)));

// round-to-nearest-even fp32 -> bf16 bits
__device__ __forceinline__ unsigned short bfr(float f){
  unsigned u = __float_as_uint(f);
  unsigned r = (u + 0x7FFFu + ((u >> 16) & 1u)) >> 16;
  return (unsigned short)r;
}

// async global->LDS, 16B per lane; lds dest is wave-uniform base (HW adds lane*16)
__device__ __forceinline__ void gload_lds16(const void* g, void* l){
  __builtin_amdgcn_global_load_lds((const __attribute__((address_space(1))) unsigned int*)g,
                                   (__attribute__((address_space(3))) unsigned int*)l,
                                   16, 0, 0);
}

// ---------------------------------------------------------------- cast x -> bf16
__global__ __launch_bounds__(256) void cast_x_kernel(const float* __restrict__ x,
                                                     unsigned short* __restrict__ xb){
  int i = blockIdx.x * 256 + threadIdx.x;           // over float4s: NT*D/4 = 1M
  const float4 v = ((const float4*)x)[i];
  unsigned short r0 = bfr(v.x), r1 = bfr(v.y), r2 = bfr(v.z), r3 = bfr(v.w);
  unsigned int p0 = (unsigned int)r0 | ((unsigned int)r1 << 16);
  unsigned int p1 = (unsigned int)r2 | ((unsigned int)r3 << 16);
  ((uint2*)xb)[i] = make_uint2(p0, p1);
}

// ------------------------- cast+transpose [R][C] f32 -> [C][R] bf16, 64x64 tiles
__global__ __launch_bounds__(256) void transpose_cast64(const float* __restrict__ in,
                                                        unsigned short* __restrict__ out,
                                                        int R, int C){
  __shared__ float t[64][65];
  long long base = (long long)blockIdx.z * R * C;
  int c0 = blockIdx.x * 64, r0 = blockIdx.y * 64;
  int tid = threadIdx.x;
  int rr = tid >> 4;           // 0..15
  int cc = (tid & 15) * 4;     // 0,4,...,60
  #pragma unroll
  for (int i = 0; i < 4; i++){
    int r = rr + i * 16;
    float4 v = *(const float4*)&in[base + (long long)(r0 + r) * C + c0 + cc];
    t[r][cc] = v.x; t[r][cc+1] = v.y; t[r][cc+2] = v.z; t[r][cc+3] = v.w;
  }
  __syncthreads();
  #pragma unroll
  for (int i = 0; i < 4; i++){
    int oc = rr + i * 16;      // output row (= input col)
    unsigned int lo = (unsigned int)bfr(t[cc][oc])   | ((unsigned int)bfr(t[cc+1][oc]) << 16);
    unsigned int hi = (unsigned int)bfr(t[cc+2][oc]) | ((unsigned int)bfr(t[cc+3][oc]) << 16);
    *(uint2*)&out[base + (long long)(c0 + oc) * R + r0 + cc] = make_uint2(lo, hi);
  }
}

// ---------------------------------------------------------------- gating (top-2)
__global__ __launch_bounds__(256) void gating_kernel(const float* __restrict__ x,
                                                     const float* __restrict__ Wg,
                                                     const float* __restrict__ bg,
                                                     int*   __restrict__ pe,
                                                     float* __restrict__ pw){
  int wid = threadIdx.x >> 6, lane = threadIdx.x & 63;
  int t = blockIdx.x * 4 + wid;
  const float* xr = x + (long long)t * D_DIM;
  float acc[E_NUM];
  #pragma unroll
  for (int e = 0; e < E_NUM; e++) acc[e] = 0.f;
  for (int d = lane; d < D_DIM; d += 64){
    float xv = xr[d];
    const float* wr = Wg + d * E_NUM;
    #pragma unroll
    for (int e = 0; e < E_NUM; e++) acc[e] += xv * wr[e];
  }
  #pragma unroll
  for (int off = 32; off; off >>= 1)
    #pragma unroll
    for (int e = 0; e < E_NUM; e++) acc[e] += __shfl_xor(acc[e], off);
  if (lane == 0){
    float l[E_NUM];
    float m = -1e30f;
    #pragma unroll
    for (int e = 0; e < E_NUM; e++){ l[e] = acc[e] + bg[e]; m = fmaxf(m, l[e]); }
    float ex[E_NUM];
    #pragma unroll
    for (int e = 0; e < E_NUM; e++) ex[e] = expf(l[e] - m);
    int e0 = 0;
    #pragma unroll
    for (int e = 1; e < E_NUM; e++) if (ex[e] > ex[e0]) e0 = e;      // first max
    int e1 = -1;
    for (int e = 0; e < E_NUM; e++){ if (e == e0) continue; if (e1 < 0 || ex[e] > ex[e1]) e1 = e; }
    float s = ex[e0] + ex[e1];
    pe[2*t]   = e0;  pw[2*t]   = ex[e0] / s;
    pe[2*t+1] = e1;  pw[2*t+1] = ex[e1] / s;
  }
}

// ---------------------------------------------------------------- chunk histograms
__global__ __launch_bounds__(256) void hist_kernel(const int* __restrict__ pe,
                                                   int* __restrict__ chunk_hist){
  __shared__ int h[E_NUM];
  if (threadIdx.x < E_NUM) h[threadIdx.x] = 0;
  __syncthreads();
  int p = blockIdx.x * 256 + threadIdx.x;
  atomicAdd(&h[pe[p]], 1);
  __syncthreads();
  if (threadIdx.x < E_NUM) chunk_hist[blockIdx.x * E_NUM + threadIdx.x] = h[threadIdx.x];
}

// --------------------------------- scan + deterministic scatter + work-item table
__global__ __launch_bounds__(256) void scatter_kernel(const int* __restrict__ pe,
                                                      const int* __restrict__ chunk_hist,
                                                      int* __restrict__ cnt,
                                                      int* __restrict__ offs,
                                                      int* __restrict__ row_pair,
                                                      int* __restrict__ wi){
  __shared__ int hist[32][E_NUM];
  __shared__ int pref[32][E_NUM];
  __shared__ int total[E_NUM];
  __shared__ int off_s[E_NUM + 1];
  __shared__ unsigned char ex[PAIRS];
  int tid = threadIdx.x;
  for (int i = tid; i < PAIRS; i += 256) ex[i] = (unsigned char)pe[i];
  { int c = tid >> 3, e = tid & 7; hist[c][e] = chunk_hist[tid]; }
  __syncthreads();
  if (tid < E_NUM){
    int s = 0;
    for (int c = 0; c < 32; c++){ pref[c][tid] = s; s += hist[c][tid]; }
    total[tid] = s;
  }
  __syncthreads();
  if (tid == 0){
    int s = 0;
    for (int e = 0; e < E_NUM; e++){ off_s[e] = s; s += total[e]; }
    off_s[E_NUM] = s;
    // work-item table: (e<<8)|mt for every valid 256-row m-tile, -1 padding
    int idx = 0;
    for (int e = 0; e < E_NUM; e++){
      int mts = (total[e] + 255) >> 8;
      for (int m = 0; m < mts; m++) wi[idx++] = (e << 8) | m;
    }
    for (; idx < WI_SLOTS; idx++) wi[idx] = -1;
  }
  __syncthreads();
  if (tid < E_NUM){ cnt[tid] = total[tid]; offs[tid] = off_s[tid]; }
  int c = tid >> 3, e = tid & 7;
  int base = off_s[e] + pref[c][e];
  int local = 0;
  for (int i = 0; i < 256; i++){
    int p = c * 256 + i;
    if (ex[p] == (unsigned char)e){
      row_pair[base + local] = p;
      local++;
    }
  }
}

// ================= shared 8-phase K-loop machinery (m201-style) =================
// Per K-tile: 4 phases. Phase p: {ds_read frags; stage ONE half-tile; barrier;
// lgkmcnt(0); setprio(1) 16 MFMA setprio(0); barrier}. Stage stream for tile k:
// p0/p1 -> A0/A1(k+1) into other buf (region dead: its tile was read last pair);
// p2/p3 -> B0/B1(k+2) into own buf (B dead after p0's reads + barrier).
// vmcnt(4) once per K-tile at p3: next tile fully landed, 2 halves stay in flight.

#define PH_SYNC \
  __builtin_amdgcn_s_barrier(); \
  asm volatile("s_waitcnt lgkmcnt(0)" ::: "memory"); \
  __builtin_amdgcn_sched_barrier(0);

#define TILE4(b, SA, SB, VMSTR) { \
  bf16x8 aq[2][2]; \
  RD_B(b); RD_A(b, 0, aq); \
  if (SA) STG_A((b)^1, 0); \
  PH_SYNC; MM(0, aq); __builtin_amdgcn_s_barrier(); \
  RD_A(b, 1, aq); \
  if (SA) STG_A((b)^1, 1); \
  PH_SYNC; MM(1, aq); __builtin_amdgcn_s_barrier(); \
  RD_A(b, 2, aq); \
  if (SB) STG_B(b, 0); \
  PH_SYNC; MM(2, aq); __builtin_amdgcn_s_barrier(); \
  RD_A(b, 3, aq); \
  if (SB) STG_B(b, 1); \
  asm volatile(VMSTR ::: "memory"); \
  PH_SYNC; MM(3, aq); __builtin_amdgcn_s_barrier(); \
}

// ============================================================== grouped GEMM1
// 256x256 tile, BK=64, 512 thr (8 waves 2x4), per-wave out 128x64.
// hidden[pos][h] = relu( x[token(pos)] . W1[e][:, h] + b1[e][h] ), bf16 out
#define CH1  80    // (16 nt * 40 slots) / 8 XCDs
__global__ __launch_bounds__(512, 2) void gemm1_kernel(const unsigned short* __restrict__ xb,
                                                       const unsigned short* __restrict__ W1t,
                                                       const float* __restrict__ b1,
                                                       const int* __restrict__ row_pair,
                                                       const int* __restrict__ cnt,
                                                       const int* __restrict__ offs,
                                                       const int* __restrict__ wi,
                                                       unsigned short* __restrict__ hidden){
  int f  = blockIdx.y * 16 + blockIdx.x;
  int fp = (f & 7) * CH1 + (f >> 3);      // bijective: 640 % 8 == 0
  int nt   = fp & 15;
  int slot = fp >> 4;
  int w = wi[slot];
  if (w < 0) return;
  int e = w >> 8, mt = w & 255;
  int count = cnt[e];
  int m0 = mt * 256;
  int seg = offs[e];
  int valid = count - m0;
  int n0 = nt * 256;

  __shared__ unsigned short As[2][256 * BK];
  __shared__ unsigned short Bs[2][256 * BK];

  int tid = threadIdx.x;
  int wv = tid >> 6, lane = tid & 63;
  int wr = wv >> 2, wc = wv & 3;          // wave rows wr*128..+127, cols wc*64..+63
  int lo = lane & 15, hi = lane >> 4;
  int l3 = lane >> 3;
  int srcel = ((lane & 7) ^ l3) << 3;     // inverse-swizzled source column (elements)

  const unsigned short* w1e = W1t + (long long)e * H_DIM * D_DIM;   // [H][D]

  const unsigned short* pa[2][2];
  const unsigned short* pb[2][2];
  #pragma unroll
  for (int h = 0; h < 2; h++)
    #pragma unroll
    for (int g = 0; g < 2; g++){
      int rloc = h * 128 + wv * 16 + g * 8 + l3;
      int pos = seg + m0 + rloc; if (pos > PAIRS - 1) pos = PAIRS - 1;
      int token = row_pair[pos] >> 1;
      pa[h][g] = xb + (long long)token * D_DIM + srcel;
      pb[h][g] = w1e + (long long)(n0 + rloc) * D_DIM + srcel;
    }

  auto STG_A = [&](int b, int h){
    gload_lds16(pa[h][0], &As[b][(h*128 + wv*16    ) * BK]);  pa[h][0] += BK;
    gload_lds16(pa[h][1], &As[b][(h*128 + wv*16 + 8) * BK]);  pa[h][1] += BK;
  };
  auto STG_B = [&](int b, int h){
    gload_lds16(pb[h][0], &Bs[b][(h*128 + wv*16    ) * BK]);  pb[h][0] += BK;
    gload_lds16(pb[h][1], &Bs[b][(h*128 + wv*16 + 8) * BK]);  pb[h][1] += BK;
  };

  f32x4 acc[8][4] = {};
  bf16x8 bq[4][2];
  auto RD_B = [&](int b){
    #pragma unroll
    for (int n = 0; n < 4; n++)
      #pragma unroll
      for (int ks = 0; ks < 2; ks++){
        int br = wc*64 + n*16 + lo;
        bq[n][ks] = *(const bf16x8*)&Bs[b][br*BK + ((ks*32 + hi*8) ^ ((br & 7) << 3))];
      }
  };
  auto RD_A = [&](int b, int s, bf16x8 (&aq)[2][2]){
    #pragma unroll
    for (int i = 0; i < 2; i++)
      #pragma unroll
      for (int ks = 0; ks < 2; ks++){
        int ar = wr*128 + (s*2 + i)*16 + lo;
        aq[i][ks] = *(const bf16x8*)&As[b][ar*BK + ((ks*32 + hi*8) ^ ((ar & 7) << 3))];
      }
  };
  auto MM = [&](int s, bf16x8 (&aq)[2][2]){
    __builtin_amdgcn_s_setprio(1);
    #pragma unroll
    for (int i = 0; i < 2; i++)
      #pragma unroll
      for (int n = 0; n < 4; n++)
        #pragma unroll
        for (int ks = 0; ks < 2; ks++)
          acc[s*2+i][n] = __builtin_amdgcn_mfma_f32_16x16x32_bf16(aq[i][ks], bq[n][ks], acc[s*2+i][n], 0, 0, 0);
    __builtin_amdgcn_s_setprio(0);
  };

  const int KT = D_DIM / BK;                 // 16
  // prologue: tile0 (B,A) + tile1 B -> 12 loads; vmcnt(4) leaves t1.B in flight
  STG_B(0, 0); STG_B(0, 1); STG_A(0, 0); STG_A(0, 1); STG_B(1, 0); STG_B(1, 1);
  asm volatile("s_waitcnt vmcnt(4)" ::: "memory");
  __builtin_amdgcn_s_barrier();
  for (int i = 0; i < KT/2 - 1; ++i){
    TILE4(0, 1, 1, "s_waitcnt vmcnt(4)");
    TILE4(1, 1, 1, "s_waitcnt vmcnt(4)");
  }
  TILE4(0, 1, 0, "s_waitcnt vmcnt(0)");      // tile KT-2: stage A(KT-1) only
  TILE4(1, 0, 0, "");                        // tile KT-1: no staging

  const float* b1e = b1 + (long long)e * H_DIM;
  #pragma unroll
  for (int n = 0; n < 4; n++){
    int col = n0 + wc*64 + n*16 + lo;
    float bias = b1e[col];
    #pragma unroll
    for (int m = 0; m < 8; m++)
      #pragma unroll
      for (int j = 0; j < 4; j++){
        int rl = wr*128 + m*16 + hi*4 + j;
        if (rl < valid){
          float v = acc[m][n][j] + bias;
          v = v > 0.f ? v : 0.f;
          hidden[(long long)(seg + m0 + rl) * H_DIM + col] = bfr(v);
        }
      }
  }
}

// ============================================================== grouped GEMM2
// same structure; split-K x2 (blockIdx.z), y = hidden . W2[e]^T (scattered out)
#define CH2  40    // (4 nt * 40 slots * 2 kparts) / 8 XCDs
__global__ __launch_bounds__(512, 2) void gemm2_kernel(const unsigned short* __restrict__ hidden,
                                                       const unsigned short* __restrict__ W2t,
                                                       const int* __restrict__ row_pair,
                                                       const int* __restrict__ cnt,
                                                       const int* __restrict__ offs,
                                                       const int* __restrict__ wi,
                                                       float* __restrict__ y0,
                                                       float* __restrict__ y1){
  int f  = (blockIdx.z * WI_SLOTS + blockIdx.y) * 4 + blockIdx.x;
  int fp = (f & 7) * CH2 + (f >> 3);      // bijective: 320 % 8 == 0
  int nt    = fp & 3;
  int r2    = fp >> 2;
  int kpart = r2 / WI_SLOTS;
  int slot  = r2 % WI_SLOTS;
  int w = wi[slot];
  if (w < 0) return;
  int e = w >> 8, mt = w & 255;
  int count = cnt[e];
  int m0 = mt * 256;
  int seg = offs[e];
  int valid = count - m0;
  int n0 = nt * 256;
  int k0 = kpart * (H_DIM / 2);
  float* y = kpart ? y1 : y0;

  __shared__ unsigned short As[2][256 * BK];
  __shared__ unsigned short Bs[2][256 * BK];

  int tid = threadIdx.x;
  int wv = tid >> 6, lane = tid & 63;
  int wr = wv >> 2, wc = wv & 3;
  int lo = lane & 15, hi = lane >> 4;
  int l3 = lane >> 3;
  int srcel = ((lane & 7) ^ l3) << 3;

  const unsigned short* w2e = W2t + (long long)e * O_DIM * H_DIM;   // [O][H]

  const unsigned short* pa[2][2];
  const unsigned short* pb[2][2];
  #pragma unroll
  for (int h = 0; h < 2; h++)
    #pragma unroll
    for (int g = 0; g < 2; g++){
      int rloc = h * 128 + wv * 16 + g * 8 + l3;
      long long pos = seg + m0 + rloc; if (pos > PAIRS - 1) pos = PAIRS - 1;
      pa[h][g] = hidden + pos * H_DIM + k0 + srcel;
      pb[h][g] = w2e + (long long)(n0 + rloc) * H_DIM + k0 + srcel;
    }

  auto STG_A = [&](int b, int h){
    gload_lds16(pa[h][0], &As[b][(h*128 + wv*16    ) * BK]);  pa[h][0] += BK;
    gload_lds16(pa[h][1], &As[b][(h*128 + wv*16 + 8) * BK]);  pa[h][1] += BK;
  };
  auto STG_B = [&](int b, int h){
    gload_lds16(pb[h][0], &Bs[b][(h*128 + wv*16    ) * BK]);  pb[h][0] += BK;
    gload_lds16(pb[h][1], &Bs[b][(h*128 + wv*16 + 8) * BK]);  pb[h][1] += BK;
  };

  f32x4 acc[8][4] = {};
  bf16x8 bq[4][2];
  auto RD_B = [&](int b){
    #pragma unroll
    for (int n = 0; n < 4; n++)
      #pragma unroll
      for (int ks = 0; ks < 2; ks++){
        int br = wc*64 + n*16 + lo;
        bq[n][ks] = *(const bf16x8*)&Bs[b][br*BK + ((ks*32 + hi*8) ^ ((br & 7) << 3))];
      }
  };
  auto RD_A = [&](int b, int s, bf16x8 (&aq)[2][2]){
    #pragma unroll
    for (int i = 0; i < 2; i++)
      #pragma unroll
      for (int ks = 0; ks < 2; ks++){
        int ar = wr*128 + (s*2 + i)*16 + lo;
        aq[i][ks] = *(const bf16x8*)&As[b][ar*BK + ((ks*32 + hi*8) ^ ((ar & 7) << 3))];
      }
  };
  auto MM = [&](int s, bf16x8 (&aq)[2][2]){
    __builtin_amdgcn_s_setprio(1);
    #pragma unroll
    for (int i = 0; i < 2; i++)
      #pragma unroll
      for (int n = 0; n < 4; n++)
        #pragma unroll
        for (int ks = 0; ks < 2; ks++)
          acc[s*2+i][n] = __builtin_amdgcn_mfma_f32_16x16x32_bf16(aq[i][ks], bq[n][ks], acc[s*2+i][n], 0, 0, 0);
    __builtin_amdgcn_s_setprio(0);
  };

  const int KT = (H_DIM / 2) / BK;           // 32
  STG_B(0, 0); STG_B(0, 1); STG_A(0, 0); STG_A(0, 1); STG_B(1, 0); STG_B(1, 1);
  asm volatile("s_waitcnt vmcnt(4)" ::: "memory");
  __builtin_amdgcn_s_barrier();
  for (int i = 0; i < KT/2 - 1; ++i){
    TILE4(0, 1, 1, "s_waitcnt vmcnt(4)");
    TILE4(1, 1, 1, "s_waitcnt vmcnt(4)");
  }
  TILE4(0, 1, 0, "s_waitcnt vmcnt(0)");
  TILE4(1, 0, 0, "");

  #pragma unroll
  for (int m = 0; m < 8; m++)
    #pragma unroll
    for (int j = 0; j < 4; j++){
      int rl = wr*128 + m*16 + hi*4 + j;
      if (rl < valid){
        int p = row_pair[seg + m0 + rl];
        float* yr = y + (long long)p * O_DIM;
        #pragma unroll
        for (int n = 0; n < 4; n++){
          int col = n0 + wc*64 + n*16 + lo;
          yr[col] = acc[m][n][j];
        }
      }
    }
}

// ---------------------------------------------------------------- combine
__global__ __launch_bounds__(256) void combine_kernel(const float* __restrict__ y0,
                                                      const float* __restrict__ y1,
                                                      const float* __restrict__ b2,
                                                      const int* __restrict__ pe,
                                                      const float* __restrict__ pw,
                                                      float* __restrict__ out){
  int t = blockIdx.x, tid = threadIdx.x;      // 256 threads * float4 = 1024 = O_DIM
  int e0 = pe[2*t], e1 = pe[2*t+1];
  float w0 = pw[2*t], w1 = pw[2*t+1];
  const float4* a0 = (const float4*)(y0 + (long long)(2*t) * O_DIM);
  const float4* a1 = (const float4*)(y1 + (long long)(2*t) * O_DIM);
  const float4* b0 = (const float4*)(y0 + (long long)(2*t+1) * O_DIM);
  const float4* b1v = (const float4*)(y1 + (long long)(2*t+1) * O_DIM);
  const float4* c0 = (const float4*)(b2 + (long long)e0 * O_DIM);
  const float4* c1 = (const float4*)(b2 + (long long)e1 * O_DIM);
  float4 xa = a0[tid], xb = a1[tid], ya = b0[tid], yb = b1v[tid], ca = c0[tid], cb = c1[tid];
  float4 r;
  r.x = w0 * (xa.x + xb.x + ca.x) + w1 * (ya.x + yb.x + cb.x);
  r.y = w0 * (xa.y + xb.y + ca.y) + w1 * (ya.y + yb.y + cb.y);
  r.z = w0 * (xa.z + xb.z + ca.z) + w1 * (ya.z + yb.z + cb.z);
  r.w = w0 * (xa.w + xb.w + ca.w) + w1 * (ya.w + yb.w + cb.w);
  ((float4*)(out + (long long)t * O_DIM))[tid] = r;
}

// ---------------------------------------------------------------- host
extern "C" void kernel_launch(void* const* d_in, const int* in_sizes, int n_in,
                              void* d_out, int out_size, void* d_ws, size_t ws_size,
                              hipStream_t stream){
  const float* x  = (const float*)d_in[0];
  const float* Wg = (const float*)d_in[1];
  const float* bg = (const float*)d_in[2];
  const float* W1 = (const float*)d_in[3];
  const float* b1 = (const float*)d_in[4];
  const float* W2 = (const float*)d_in[5];
  const float* b2 = (const float*)d_in[6];
  float* out = (float*)d_out;

  char* ws = (char*)d_ws;
  size_t off = 0;
  auto alloc = [&](size_t bytes){ size_t r = off; off += (bytes + 255) & ~(size_t)255; return r; };

  unsigned short* W1t    = (unsigned short*)(ws + alloc((size_t)E_NUM * H_DIM * D_DIM * 2));
  unsigned short* W2t    = (unsigned short*)(ws + alloc((size_t)E_NUM * O_DIM * H_DIM * 2));
  unsigned short* xb     = (unsigned short*)(ws + alloc((size_t)NT_TOK * D_DIM * 2));
  unsigned short* hidden = (unsigned short*)(ws + alloc((size_t)PAIRS * H_DIM * 2));
  float*          y_p0   = (float*)         (ws + alloc((size_t)PAIRS * O_DIM * 4));
  int*            pe     = (int*)           (ws + alloc(PAIRS * 4));
  float*          pw     = (float*)         (ws + alloc(PAIRS * 4));
  int*            row_pair = (int*)         (ws + alloc(PAIRS * 4));
  int*            cnt    = (int*)           (ws + alloc(64));
  int*            offs   = (int*)           (ws + alloc(64));
  int*            chist  = (int*)           (ws + alloc(32 * E_NUM * 4));
  int*            wi     = (int*)           (ws + alloc(WI_SLOTS * 4));
  // y partial 1 aliases W1t (dead after gemm1; stream order guarantees safety)
  float*          y_p1   = (float*)W1t;

  if (off > ws_size)
    fprintf(stderr, "kernel_launch: workspace too small: need %zu, have %zu\n", off, ws_size);

  cast_x_kernel<<<(NT_TOK * D_DIM / 4) / 256, 256, 0, stream>>>(x, xb);
  transpose_cast64<<<dim3(H_DIM/64, D_DIM/64, E_NUM), 256, 0, stream>>>(W1, W1t, D_DIM, H_DIM);
  transpose_cast64<<<dim3(O_DIM/64, H_DIM/64, E_NUM), 256, 0, stream>>>(W2, W2t, H_DIM, O_DIM);
  gating_kernel<<<NT_TOK/4, 256, 0, stream>>>(x, Wg, bg, pe, pw);
  hist_kernel<<<PAIRS/256, 256, 0, stream>>>(pe, chist);
  scatter_kernel<<<1, 256, 0, stream>>>(pe, chist, cnt, offs, row_pair, wi);
  gemm1_kernel<<<dim3(H_DIM/256, WI_SLOTS), 512, 0, stream>>>(xb, W1t, b1, row_pair, cnt, offs, wi, hidden);
  gemm2_kernel<<<dim3(O_DIM/256, WI_SLOTS, 2), 512, 0, stream>>>(hidden, W2t, row_pair, cnt, offs, wi, y_p0, y_p1);
  combine_kernel<<<NT_TOK, 256, 0, stream>>>(y_p0, y_p1, b2, pe, pw, out);
}